// Round 1
// baseline (175.603 us; speedup 1.0000x reference)
//
#include <hip/hip_runtime.h>

// ContrastiveTreeLoss: out = mean_{k,b} max(MARGIN - gold_total[b] + neg_total[k,b], 0)
//   gold_total[b]  = sum_{d=0..N-2} arc[b, clip(gold[b,d+1]), d+1] * mask[b,d+1]
//   neg_total[k,b] = sum_{d=0..N-2} arc[b, clip(neg[k,b,d+1]), d+1] * mask[b,d+1]
// Shapes: arc [B,N,N] f32, gold [B,N] i32, mask [B,N] i32, negs [K,B,N] i32.
// B=512, N=256, K=4, MARGIN=2.0. Output: 1 float.

#define B_DIM 512
#define N_DIM 256
#define K_NEG 4
#define MARGIN_F 2.0f

__global__ __launch_bounds__(256) void ContrastiveTreeLoss_kernel(
    const float* __restrict__ arc,   // [B,N,N]
    const int*   __restrict__ gold,  // [B,N]
    const int*   __restrict__ mask,  // [B,N]
    const int*   __restrict__ negs,  // [K,B,N]
    float*       __restrict__ out)   // [1]
{
    const int b = blockIdx.x;
    const int t = threadIdx.x;       // 0..255; dependent index d = t, column = d+1

    float v[1 + K_NEG];
    #pragma unroll
    for (int i = 0; i < 1 + K_NEG; ++i) v[i] = 0.0f;

    if (t < N_DIM - 1) {
        const int col = t + 1;
        const float m = (float)mask[b * N_DIM + col];
        const float* arc_bc = arc + (size_t)b * N_DIM * N_DIM + col;

        int gh = gold[b * N_DIM + col];
        gh = min(max(gh, 0), N_DIM - 1);
        v[0] = arc_bc[(size_t)gh * N_DIM] * m;

        #pragma unroll
        for (int k = 0; k < K_NEG; ++k) {
            int nh = negs[(size_t)k * B_DIM * N_DIM + b * N_DIM + col];
            nh = min(max(nh, 0), N_DIM - 1);
            v[1 + k] = arc_bc[(size_t)nh * N_DIM] * m;
        }
    }

    // Wave (64-lane) shuffle reduction of the 5 partial sums.
    #pragma unroll
    for (int off = 32; off > 0; off >>= 1) {
        #pragma unroll
        for (int i = 0; i < 1 + K_NEG; ++i)
            v[i] += __shfl_down(v[i], off, 64);
    }

    __shared__ float part[4][1 + K_NEG];  // 4 waves per 256-thread block
    const int lane = t & 63;
    const int wave = t >> 6;
    if (lane == 0) {
        #pragma unroll
        for (int i = 0; i < 1 + K_NEG; ++i) part[wave][i] = v[i];
    }
    __syncthreads();

    if (t == 0) {
        float s[1 + K_NEG];
        #pragma unroll
        for (int i = 0; i < 1 + K_NEG; ++i)
            s[i] = part[0][i] + part[1][i] + part[2][i] + part[3][i];
        float loss = 0.0f;
        #pragma unroll
        for (int k = 0; k < K_NEG; ++k)
            loss += fmaxf(MARGIN_F - s[0] + s[1 + k], 0.0f);
        atomicAdd(out, loss * (1.0f / (K_NEG * B_DIM)));
    }
}

extern "C" void kernel_launch(void* const* d_in, const int* in_sizes, int n_in,
                              void* d_out, int out_size, void* d_ws, size_t ws_size,
                              hipStream_t stream) {
    const float* arc  = (const float*)d_in[0];  // [B,N,N]
    const int*   gold = (const int*)  d_in[1];  // [B,N]
    const int*   mask = (const int*)  d_in[2];  // [B,N]
    const int*   negs = (const int*)  d_in[3];  // [K,B,N]
    float*       out  = (float*)d_out;

    // d_out is poisoned 0xAA before every call; zero it (capture-safe memset node).
    hipMemsetAsync(out, 0, sizeof(float), stream);

    ContrastiveTreeLoss_kernel<<<B_DIM, 256, 0, stream>>>(arc, gold, mask, negs, out);
}

// Round 2
// 172.291 us; speedup vs baseline: 1.0192x; 1.0192x over previous
//
#include <hip/hip_runtime.h>

// ContrastiveTreeLoss: out = mean_{k,b} max(MARGIN - gold_total[b] + neg_total[k,b], 0)
//
// Key identity: each negative head list differs from gold in at most 2
// positions (a swap), so gold_total cancels:
//   margin - gold + neg = margin + sum_{d: nh!=gh} (arc[b,nh,d] - arc[b,gh,d]) * m[b,d]
// => only ~4 scattered arc loads per (k,b) instead of 5*255 per sentence.
//
// Shapes: arc [B,N,N] f32, gold [B,N] i32, mask [B,N] i32, negs [K,B,N] i32.
// B=512, N=256, K=4, MARGIN=2.0. Output: 1 float.

#define B_DIM 512
#define N_DIM 256
#define K_NEG 4
#define MARGIN_F 2.0f

__global__ __launch_bounds__(256) void ContrastiveTreeLoss_kernel(
    const float* __restrict__ arc,   // [B,N,N]
    const int*   __restrict__ gold,  // [B,N]
    const int*   __restrict__ mask,  // [B,N]
    const int*   __restrict__ negs,  // [K,B,N]
    float*       __restrict__ out)   // [1]
{
    const int b = blockIdx.x;
    const int t = threadIdx.x;       // dependent d = t, column = t+1

    float dk[K_NEG];
    #pragma unroll
    for (int k = 0; k < K_NEG; ++k) dk[k] = 0.0f;

    if (t < N_DIM - 1) {
        const int col = t + 1;
        const float m = (float)mask[b * N_DIM + col];
        const float* arc_b = arc + (size_t)b * N_DIM * N_DIM;

        int gh = gold[b * N_DIM + col];
        gh = min(max(gh, 0), N_DIM - 1);

        #pragma unroll
        for (int k = 0; k < K_NEG; ++k) {
            int nh = negs[(size_t)k * B_DIM * N_DIM + b * N_DIM + col];
            nh = min(max(nh, 0), N_DIM - 1);
            if (nh != gh) {
                // Rare path: ~2 lanes per (k, sentence). Exec-masked gathers.
                float gval = arc_b[(size_t)gh * N_DIM + col];
                float nval = arc_b[(size_t)nh * N_DIM + col];
                dk[k] = (nval - gval) * m;
            }
        }
    }

    // Wave (64-lane) shuffle reduction of the 4 per-negative deltas.
    #pragma unroll
    for (int off = 32; off > 0; off >>= 1) {
        #pragma unroll
        for (int k = 0; k < K_NEG; ++k)
            dk[k] += __shfl_down(dk[k], off, 64);
    }

    __shared__ float part[4][K_NEG];  // 4 waves per 256-thread block
    const int lane = t & 63;
    const int wave = t >> 6;
    if (lane == 0) {
        #pragma unroll
        for (int k = 0; k < K_NEG; ++k) part[wave][k] = dk[k];
    }
    __syncthreads();

    if (t == 0) {
        float loss = 0.0f;
        #pragma unroll
        for (int k = 0; k < K_NEG; ++k) {
            float delta = part[0][k] + part[1][k] + part[2][k] + part[3][k];
            loss += fmaxf(MARGIN_F + delta, 0.0f);
        }
        atomicAdd(out, loss * (1.0f / (K_NEG * B_DIM)));
    }
}

extern "C" void kernel_launch(void* const* d_in, const int* in_sizes, int n_in,
                              void* d_out, int out_size, void* d_ws, size_t ws_size,
                              hipStream_t stream) {
    const float* arc  = (const float*)d_in[0];  // [B,N,N]
    const int*   gold = (const int*)  d_in[1];  // [B,N]
    const int*   mask = (const int*)  d_in[2];  // [B,N]
    const int*   negs = (const int*)  d_in[3];  // [K,B,N]
    float*       out  = (float*)d_out;

    // d_out is poisoned 0xAA before every call; zero it (capture-safe memset node).
    hipMemsetAsync(out, 0, sizeof(float), stream);

    ContrastiveTreeLoss_kernel<<<B_DIM, 256, 0, stream>>>(arc, gold, mask, negs, out);
}